// Round 1
// baseline (688.629 us; speedup 1.0000x reference)
//
#include <hip/hip_runtime.h>

// Problem constants (match reference)
#define N_ITEMS   64
#define CAPACITY  102.0f
#define N_BISECT  60
#define N_PGD     120
#define ETA       0.1f

// ---- DPP helpers: butterfly reductions over 8-lane groups ----------------
// All three controls act within a DPP "row" (16 lanes), and in fact within
// 8-lane halves, so an 8-lane problem-group never leaks into its neighbor:
//   0xB1  = quad_perm [1,0,3,2]  -> lane ^ 1
//   0x4E  = quad_perm [2,3,0,1]  -> lane ^ 2
//   0x141 = row_half_mirror      -> lane ^ 7 within each 8-lane half
template <int CTRL>
__device__ __forceinline__ float dpp_movf(float x) {
  return __builtin_bit_cast(
      float, __builtin_amdgcn_update_dpp(0, __builtin_bit_cast(int, x), CTRL,
                                         0xF, 0xF, true));
}

__device__ __forceinline__ float grp8_sum(float x) {
  x += dpp_movf<0xB1>(x);
  x += dpp_movf<0x4E>(x);
  x += dpp_movf<0x141>(x);
  return x;  // all 8 lanes hold the (bitwise-identical) group sum
}

__device__ __forceinline__ float grp8_max(float x) {
  x = fmaxf(x, dpp_movf<0xB1>(x));
  x = fmaxf(x, dpp_movf<0x4E>(x));
  x = fmaxf(x, dpp_movf<0x141>(x));
  return x;
}

__device__ __forceinline__ float clip01(float z) {
  return __builtin_amdgcn_fmed3f(z, 0.0f, 1.0f);  // single v_med3_f32
}

// 8 lanes per row, 8 items per lane. 16384 rows -> 131072 threads.
__global__ __launch_bounds__(256, 2) void pgd_knapsack(
    const float* __restrict__ costs, const float* __restrict__ weights,
    float* __restrict__ out) {
  const int tid  = blockIdx.x * 256 + threadIdx.x;
  const int sub  = tid & 7;                 // lane within row-group
  const int base = (tid >> 3) * N_ITEMS + sub * 8;

  float c[8], w[8], invw[8], ec[8], x[8], y[8];

  {
    const float4 c0 = *reinterpret_cast<const float4*>(costs + base);
    const float4 c1 = *reinterpret_cast<const float4*>(costs + base + 4);
    c[0] = c0.x; c[1] = c0.y; c[2] = c0.z; c[3] = c0.w;
    c[4] = c1.x; c[5] = c1.y; c[6] = c1.z; c[7] = c1.w;
    const float4 w0 = *reinterpret_cast<const float4*>(weights + sub * 8);
    const float4 w1 = *reinterpret_cast<const float4*>(weights + sub * 8 + 4);
    w[0] = w0.x; w[1] = w0.y; w[2] = w0.z; w[3] = w0.w;
    w[4] = w1.x; w[5] = w1.y; w[6] = w1.z; w[7] = w1.w;
  }

#pragma unroll
  for (int j = 0; j < 8; ++j) {
    invw[j] = 1.0f / w[j];
    ec[j]   = ETA * c[j];        // precomputed eta * costs for the PGD update
    y[j]    = clip01(c[j]);      // y for the very first projection
  }

#pragma unroll 1
  for (int it = 0; it <= N_PGD; ++it) {
    if (it > 0) {
      // y = x + eta*(c - x/||x||) = (1 - eta/||x||)*x + eta*c
      float a0 = x[0] * x[0];
      a0 = fmaf(x[1], x[1], a0); a0 = fmaf(x[2], x[2], a0); a0 = fmaf(x[3], x[3], a0);
      float a1 = x[4] * x[4];
      a1 = fmaf(x[5], x[5], a1); a1 = fmaf(x[6], x[6], a1); a1 = fmaf(x[7], x[7], a1);
      const float s2  = grp8_sum(a0 + a1);
      const float inv = __builtin_amdgcn_rsqf(s2 + 1e-12f);  // v_rsq_f32
      const float s   = 1.0f - ETA * inv;
#pragma unroll
      for (int j = 0; j < 8; ++j) y[j] = fmaf(s, x[j], ec[j]);
    }

    // ---- projection of y onto {0<=x<=1, w@x<=CAPACITY} ----
    // Fused pass: g(0) (feasibility) and upper bracket max(relu(y)/w).
    float g0p = 0.0f, mp = 0.0f;
#pragma unroll
    for (int j = 0; j < 8; ++j) {
      g0p = fmaf(w[j], clip01(y[j]), g0p);
      mp  = fmaxf(mp, fmaxf(y[j], 0.0f) * invw[j]);
    }
    const float g0 = grp8_sum(g0p);
    float hi = grp8_max(mp) + 1e-3f;
    float lo = 0.0f;

#pragma unroll 1
    for (int b = 0; b < N_BISECT; ++b) {
      const float mid = 0.5f * (lo + hi);
      // g(mid): 3 VALU ops per item (fma, med3, fma), two chains for ILP
      float q0 = w[0] * clip01(fmaf(-mid, w[0], y[0]));
      q0 = fmaf(w[1], clip01(fmaf(-mid, w[1], y[1])), q0);
      q0 = fmaf(w[2], clip01(fmaf(-mid, w[2], y[2])), q0);
      q0 = fmaf(w[3], clip01(fmaf(-mid, w[3], y[3])), q0);
      float q1 = w[4] * clip01(fmaf(-mid, w[4], y[4]));
      q1 = fmaf(w[5], clip01(fmaf(-mid, w[5], y[5])), q1);
      q1 = fmaf(w[6], clip01(fmaf(-mid, w[6], y[6])), q1);
      q1 = fmaf(w[7], clip01(fmaf(-mid, w[7], y[7])), q1);
      const float g = grp8_sum(q0 + q1);
      const bool over = g > CAPACITY;
      lo = over ? mid : lo;
      hi = over ? hi : mid;
    }
    float lam = 0.5f * (lo + hi);
    lam = (g0 <= CAPACITY) ? 0.0f : lam;  // constraint inactive -> lam = 0

#pragma unroll
    for (int j = 0; j < 8; ++j) x[j] = clip01(fmaf(-lam, w[j], y[j]));
  }

  *reinterpret_cast<float4*>(out + base)     = make_float4(x[0], x[1], x[2], x[3]);
  *reinterpret_cast<float4*>(out + base + 4) = make_float4(x[4], x[5], x[6], x[7]);
}

extern "C" void kernel_launch(void* const* d_in, const int* in_sizes, int n_in,
                              void* d_out, int out_size, void* d_ws, size_t ws_size,
                              hipStream_t stream) {
  const float* costs   = (const float*)d_in[0];
  const float* weights = (const float*)d_in[1];
  float* out           = (float*)d_out;

  const int n_rows  = in_sizes[0] / N_ITEMS;  // 16384
  const int threads = n_rows * 8;             // 8 lanes per row
  dim3 block(256);
  dim3 grid(threads / 256);
  pgd_knapsack<<<grid, block, 0, stream>>>(costs, weights, out);
}

// Round 2
// 391.028 us; speedup vs baseline: 1.7611x; 1.7611x over previous
//
#include <hip/hip_runtime.h>

// Problem constants (match reference)
#define N_ITEMS   64
#define CAPACITY  102.0f
#define N_PGD     120
#define ETA       0.1f
#define N_NEWTON  9   // g-evals per projection after the lam=0 eval

// ---- DPP helpers: butterfly reductions over 8-lane groups ----------------
//   0xB1  = quad_perm [1,0,3,2]  -> lane ^ 1
//   0x4E  = quad_perm [2,3,0,1]  -> lane ^ 2
//   0x141 = row_half_mirror      -> lane ^ 7 within each 8-lane half
template <int CTRL>
__device__ __forceinline__ float dpp_movf(float x) {
  return __builtin_bit_cast(
      float, __builtin_amdgcn_update_dpp(0, __builtin_bit_cast(int, x), CTRL,
                                         0xF, 0xF, true));
}

__device__ __forceinline__ float grp8_sum(float x) {
  x += dpp_movf<0xB1>(x);
  x += dpp_movf<0x4E>(x);
  x += dpp_movf<0x141>(x);
  return x;
}

__device__ __forceinline__ float grp8_max(float x) {
  x = fmaxf(x, dpp_movf<0xB1>(x));
  x = fmaxf(x, dpp_movf<0x4E>(x));
  x = fmaxf(x, dpp_movf<0x141>(x));
  return x;
}

__device__ __forceinline__ float clip01(float z) {
  return __builtin_amdgcn_fmed3f(z, 0.0f, 1.0f);  // single v_med3_f32
}

// 8 lanes per row, 8 items per lane. 16384 rows -> 131072 threads.
__global__ __launch_bounds__(256, 2) void pgd_knapsack(
    const float* __restrict__ costs, const float* __restrict__ weights,
    float* __restrict__ out) {
  const int tid  = blockIdx.x * 256 + threadIdx.x;
  const int sub  = tid & 7;                 // lane within row-group
  const int base = (tid >> 3) * N_ITEMS + sub * 8;

  float w[8], ec[8], x[8], y[8];

  {
    const float4 c0 = *reinterpret_cast<const float4*>(costs + base);
    const float4 c1 = *reinterpret_cast<const float4*>(costs + base + 4);
    const float4 w0 = *reinterpret_cast<const float4*>(weights + sub * 8);
    const float4 w1 = *reinterpret_cast<const float4*>(weights + sub * 8 + 4);
    w[0] = w0.x; w[1] = w0.y; w[2] = w0.z; w[3] = w0.w;
    w[4] = w1.x; w[5] = w1.y; w[6] = w1.z; w[7] = w1.w;
    float cc[8] = {c0.x, c0.y, c0.z, c0.w, c1.x, c1.y, c1.z, c1.w};
#pragma unroll
    for (int j = 0; j < 8; ++j) {
      ec[j] = ETA * cc[j];       // eta * costs for the PGD update
      y[j]  = clip01(cc[j]);     // y for the very first projection
      x[j]  = -1.0f;             // sentinel so the it=0 compare is well-defined
    }
  }

#pragma unroll 1
  for (int it = 0; it <= N_PGD; ++it) {
    if (it > 0) {
      // y = x + eta*(c - x/||x||) = (1 - eta/||x||)*x + eta*c
      float a0 = x[0] * x[0];
      a0 = fmaf(x[1], x[1], a0); a0 = fmaf(x[2], x[2], a0); a0 = fmaf(x[3], x[3], a0);
      float a1 = x[4] * x[4];
      a1 = fmaf(x[5], x[5], a1); a1 = fmaf(x[6], x[6], a1); a1 = fmaf(x[7], x[7], a1);
      const float s2  = grp8_sum(a0 + a1);
      const float inv = __builtin_amdgcn_rsqf(s2 + 1e-12f);
      const float s   = 1.0f - ETA * inv;
#pragma unroll
      for (int j = 0; j < 8; ++j) y[j] = fmaf(s, x[j], ec[j]);
    }

    // ---- projection of y onto {0<=x<=1, w@x<=CAPACITY} ----
    // Fused lam=0 evaluation: g(0), slope-sum d(0), and bracket bound.
    // hi = max(relu(y)) + 1e-3 >= max(relu(y)/w) since w >= 1 -> g(hi)=0.
    float g, ds;
    float lo = 0.0f, hi;
    {
      float q0 = 0.0f, q1 = 0.0f, e0 = 0.0f, e1 = 0.0f, mp = 0.0f;
#pragma unroll
      for (int j = 0; j < 4; ++j) {
        const float t = clip01(y[j]);
        q0 = fmaf(w[j], t, q0);
        const float ws = (y[j] == t) ? w[j] : 0.0f;  // strictly-interior slope
        e0 = fmaf(ws, ws, e0);
        mp = fmaxf(mp, y[j]);
      }
#pragma unroll
      for (int j = 4; j < 8; ++j) {
        const float t = clip01(y[j]);
        q1 = fmaf(w[j], t, q1);
        const float ws = (y[j] == t) ? w[j] : 0.0f;
        e1 = fmaf(ws, ws, e1);
        mp = fmaxf(mp, y[j]);
      }
      g  = grp8_sum(q0 + q1);
      ds = grp8_sum(e0 + e1);
      hi = fmaxf(grp8_max(mp), 0.0f) + 1e-3f;
    }
    const bool feas = (g <= CAPACITY);  // constraint inactive -> lam = 0
    float lam = 0.0f;

#pragma unroll 1
    for (int k = 0; k < N_NEWTON; ++k) {
      // Safeguarded-Newton pick based on the last evaluation.
      const bool over = g > CAPACITY;
      lo = over ? lam : lo;
      hi = over ? hi : lam;
      // PL-Newton: lam' = lam + (g-b)/ds  (slope is -ds, ds >= 0).
      // ds==0 -> inf/NaN -> comparison fails -> midpoint fallback.
      const float newt = fmaf(g - CAPACITY, __builtin_amdgcn_rcpf(ds), lam);
      const bool ok = (ds > 0.0f) && (newt >= lo) && (newt <= hi);
      lam = ok ? newt : 0.5f * (lo + hi);

      // Evaluate g and ds at lam (6 VALU ops/item, two chains for ILP).
      float q0, q1, e0 = 0.0f, e1 = 0.0f;
      {
        float z = fmaf(-lam, w[0], y[0]); float t = clip01(z);
        q0 = w[0] * t; float ws = (z == t) ? w[0] : 0.0f; e0 = fmaf(ws, ws, e0);
        z = fmaf(-lam, w[1], y[1]); t = clip01(z);
        q0 = fmaf(w[1], t, q0); ws = (z == t) ? w[1] : 0.0f; e0 = fmaf(ws, ws, e0);
        z = fmaf(-lam, w[2], y[2]); t = clip01(z);
        q0 = fmaf(w[2], t, q0); ws = (z == t) ? w[2] : 0.0f; e0 = fmaf(ws, ws, e0);
        z = fmaf(-lam, w[3], y[3]); t = clip01(z);
        q0 = fmaf(w[3], t, q0); ws = (z == t) ? w[3] : 0.0f; e0 = fmaf(ws, ws, e0);
        z = fmaf(-lam, w[4], y[4]); t = clip01(z);
        q1 = w[4] * t; ws = (z == t) ? w[4] : 0.0f; e1 = fmaf(ws, ws, e1);
        z = fmaf(-lam, w[5], y[5]); t = clip01(z);
        q1 = fmaf(w[5], t, q1); ws = (z == t) ? w[5] : 0.0f; e1 = fmaf(ws, ws, e1);
        z = fmaf(-lam, w[6], y[6]); t = clip01(z);
        q1 = fmaf(w[6], t, q1); ws = (z == t) ? w[6] : 0.0f; e1 = fmaf(ws, ws, e1);
        z = fmaf(-lam, w[7], y[7]); t = clip01(z);
        q1 = fmaf(w[7], t, q1); ws = (z == t) ? w[7] : 0.0f; e1 = fmaf(ws, ws, e1);
      }
      g  = grp8_sum(q0 + q1);
      ds = grp8_sum(e0 + e1);
    }
    // Final derivative-free pick from the last evaluation (no extra eval).
    {
      const bool over = g > CAPACITY;
      lo = over ? lam : lo;
      hi = over ? hi : lam;
      const float newt = fmaf(g - CAPACITY, __builtin_amdgcn_rcpf(ds), lam);
      const bool ok = (ds > 0.0f) && (newt >= lo) && (newt <= hi);
      lam = ok ? newt : 0.5f * (lo + hi);
    }
    lam = feas ? 0.0f : lam;

    // x = clip(y - lam*w); exact-fixed-point early exit (bitwise-safe:
    // the PGD map is deterministic, so x_{t+1}==x_t => all later iterates equal).
    bool eq = true;
#pragma unroll
    for (int j = 0; j < 8; ++j) {
      const float nx = clip01(fmaf(-lam, w[j], y[j]));
      eq = eq && (nx == x[j]);
      x[j] = nx;
    }
    if (it > 0 && __all(eq)) break;  // per-wave exit; no barriers/LDS in kernel
  }

  *reinterpret_cast<float4*>(out + base)     = make_float4(x[0], x[1], x[2], x[3]);
  *reinterpret_cast<float4*>(out + base + 4) = make_float4(x[4], x[5], x[6], x[7]);
}

extern "C" void kernel_launch(void* const* d_in, const int* in_sizes, int n_in,
                              void* d_out, int out_size, void* d_ws, size_t ws_size,
                              hipStream_t stream) {
  const float* costs   = (const float*)d_in[0];
  const float* weights = (const float*)d_in[1];
  float* out           = (float*)d_out;

  const int n_rows  = in_sizes[0] / N_ITEMS;  // 16384
  const int threads = n_rows * 8;             // 8 lanes per row
  dim3 block(256);
  dim3 grid(threads / 256);
  pgd_knapsack<<<grid, block, 0, stream>>>(costs, weights, out);
}

// Round 3
// 260.446 us; speedup vs baseline: 2.6440x; 1.5014x over previous
//
#include <hip/hip_runtime.h>

// Problem constants (match reference)
#define N_ITEMS   64
#define CAPACITY  102.0f
#define N_PGD     120
#define ETA       0.1f
#define N_SECANT  8   // g-evals per projection after the lam=0 eval

typedef float v2f __attribute__((ext_vector_type(2)));

// ---- DPP helpers: butterfly reductions over 8-lane groups ----------------
//   0xB1  = quad_perm [1,0,3,2]  -> lane ^ 1
//   0x4E  = quad_perm [2,3,0,1]  -> lane ^ 2
//   0x141 = row_half_mirror      -> lane ^ 7 within each 8-lane half
// FP add/max are commutative => all 8 lanes end bitwise-identical, so
// per-group control decisions are uniform within the group.
template <int CTRL>
__device__ __forceinline__ float dpp_movf(float x) {
  return __builtin_bit_cast(
      float, __builtin_amdgcn_update_dpp(0, __builtin_bit_cast(int, x), CTRL,
                                         0xF, 0xF, true));
}

__device__ __forceinline__ float grp8_sum(float x) {
  x += dpp_movf<0xB1>(x);
  x += dpp_movf<0x4E>(x);
  x += dpp_movf<0x141>(x);
  return x;
}

__device__ __forceinline__ float grp8_max(float x) {
  x = fmaxf(x, dpp_movf<0xB1>(x));
  x = fmaxf(x, dpp_movf<0x4E>(x));
  x = fmaxf(x, dpp_movf<0x141>(x));
  return x;
}

__device__ __forceinline__ float clip01(float z) {
  return __builtin_amdgcn_fmed3f(z, 0.0f, 1.0f);  // single v_med3_f32
}

// g(lam) = sum_j w_j * clip(y_j - lam*w_j, 0, 1), reduced over the 8-lane group.
__device__ __forceinline__ float eval_g(const v2f* __restrict__ w,
                                        const v2f* __restrict__ y, float lam) {
  const v2f nl = {-lam, -lam};
  // z via packed fma (v_pk_fma_f32), clip via scalar med3, accumulate scalar.
  const v2f z0 = __builtin_elementwise_fma(nl, w[0], y[0]);
  const v2f z1 = __builtin_elementwise_fma(nl, w[1], y[1]);
  const v2f z2 = __builtin_elementwise_fma(nl, w[2], y[2]);
  const v2f z3 = __builtin_elementwise_fma(nl, w[3], y[3]);
  float q0 = w[0].x * clip01(z0.x);
  q0 = fmaf(w[0].y, clip01(z0.y), q0);
  q0 = fmaf(w[1].x, clip01(z1.x), q0);
  q0 = fmaf(w[1].y, clip01(z1.y), q0);
  float q1 = w[2].x * clip01(z2.x);
  q1 = fmaf(w[2].y, clip01(z2.y), q1);
  q1 = fmaf(w[3].x, clip01(z3.x), q1);
  q1 = fmaf(w[3].y, clip01(z3.y), q1);
  return grp8_sum(q0 + q1);
}

// False-position estimate from the current bracket state.
__device__ __forceinline__ float false_pos(float lo, float flo, float hi,
                                           float fhi) {
  const float t = fhi * __builtin_amdgcn_rcpf(fhi - flo);
  return fmaf(-t, hi - lo, hi);  // hi - fhi*(hi-lo)/(fhi-flo)
}

// 8 lanes per row, 8 items per lane. 16384 rows -> 131072 threads.
__global__ __launch_bounds__(256, 2) void pgd_knapsack(
    const float* __restrict__ costs, const float* __restrict__ weights,
    float* __restrict__ out) {
  const int tid  = blockIdx.x * 256 + threadIdx.x;
  const int sub  = tid & 7;                 // lane within row-group
  const int base = (tid >> 3) * N_ITEMS + sub * 8;

  v2f w[4], ec[4], x[4], y[4];

  {
    const float4 c0 = *reinterpret_cast<const float4*>(costs + base);
    const float4 c1 = *reinterpret_cast<const float4*>(costs + base + 4);
    const float4 w0 = *reinterpret_cast<const float4*>(weights + sub * 8);
    const float4 w1 = *reinterpret_cast<const float4*>(weights + sub * 8 + 4);
    w[0] = {w0.x, w0.y}; w[1] = {w0.z, w0.w};
    w[2] = {w1.x, w1.y}; w[3] = {w1.z, w1.w};
    const float cc[8] = {c0.x, c0.y, c0.z, c0.w, c1.x, c1.y, c1.z, c1.w};
#pragma unroll
    for (int p = 0; p < 4; ++p) {
      ec[p] = (v2f){ETA * cc[2 * p], ETA * cc[2 * p + 1]};
      y[p]  = (v2f){clip01(cc[2 * p]), clip01(cc[2 * p + 1])};
      x[p]  = (v2f){-1.0f, -1.0f};  // sentinel for the it=0 fixpoint compare
    }
  }

  float lam_prev = 0.0f;  // warm start for the multiplier across PGD iters

#pragma unroll 1
  for (int it = 0; it <= N_PGD; ++it) {
    if (it > 0) {
      // y = x + eta*(c - x/||x||) = (1 - eta/||x||)*x + eta*c
      v2f a = x[0] * x[0];
      a = __builtin_elementwise_fma(x[1], x[1], a);
      v2f b = x[2] * x[2];
      b = __builtin_elementwise_fma(x[3], x[3], b);
      const v2f ab = a + b;
      const float s2  = grp8_sum(ab.x + ab.y);
      const float inv = __builtin_amdgcn_rsqf(s2 + 1e-12f);
      const float s   = 1.0f - ETA * inv;
      const v2f sv = {s, s};
#pragma unroll
      for (int p = 0; p < 4; ++p)
        y[p] = __builtin_elementwise_fma(sv, x[p], ec[p]);
    }

    // ---- projection of y onto {0<=x<=1, w@x<=CAPACITY} -------------------
    // Prologue: g(0) (feasibility + left bracket) and upper bracket.
    // hi = max(relu(y)) + 1e-3 >= max(relu(y)/w) since w >= 1, so g(hi) = 0.
    float lo = 0.0f, hi, flo;
    float fhi = -CAPACITY;  // g(hi) - CAPACITY = 0 - CAPACITY, exact
    {
      float q0 = w[0].x * clip01(y[0].x);
      q0 = fmaf(w[0].y, clip01(y[0].y), q0);
      q0 = fmaf(w[1].x, clip01(y[1].x), q0);
      q0 = fmaf(w[1].y, clip01(y[1].y), q0);
      float q1 = w[2].x * clip01(y[2].x);
      q1 = fmaf(w[2].y, clip01(y[2].y), q1);
      q1 = fmaf(w[3].x, clip01(y[3].x), q1);
      q1 = fmaf(w[3].y, clip01(y[3].y), q1);
      const float g0 = grp8_sum(q0 + q1);
      flo = g0 - CAPACITY;
      const v2f m01 = __builtin_elementwise_max(y[0], y[1]);
      const v2f m23 = __builtin_elementwise_max(y[2], y[3]);
      const v2f mm  = __builtin_elementwise_max(m01, m23);
      hi = fmaxf(grp8_max(fmaxf(mm.x, mm.y)), 0.0f) + 1e-3f;
    }
    const bool feas = (flo <= 0.0f);  // constraint inactive -> lam = 0
    bool prevpos = false;
    float lam;

    // Illinois-safeguarded secant. g is monotone PL, so once the bracket is
    // inside one segment false position is exact; Illinois halving prevents
    // one-sided stagnation. Bad picks (inf/NaN/outside) fall back to midpoint.
    {  // first probe: warm start from the previous iteration's multiplier
      const float fp   = false_pos(lo, flo, hi, fhi);
      const bool okfp  = (fp > lo) && (fp < hi);
      const float cand = okfp ? fp : 0.5f * (lo + hi);
      const bool okw   = (lam_prev > lo) && (lam_prev < hi);
      lam = okw ? lam_prev : cand;
      const float f = eval_g(w, y, lam) - CAPACITY;
      const bool pos = f > 0.0f;
      flo = pos ? f : flo;
      lo  = pos ? lam : lo;
      fhi = pos ? fhi : f;
      hi  = pos ? hi : lam;
      prevpos = pos;
    }
#pragma unroll 1
    for (int k = 1; k < N_SECANT; ++k) {
      const float fp  = false_pos(lo, flo, hi, fhi);
      const bool okfp = (fp > lo) && (fp < hi);
      lam = okfp ? fp : 0.5f * (lo + hi);
      const float f = eval_g(w, y, lam) - CAPACITY;
      const bool pos = f > 0.0f;
      const bool rep = (pos == prevpos);
      flo = pos ? f : (rep ? 0.5f * flo : flo);
      lo  = pos ? lam : lo;
      fhi = pos ? (rep ? 0.5f * fhi : fhi) : f;
      hi  = pos ? hi : lam;
      prevpos = pos;
    }
    {  // final derivative-free pick (no extra eval); non-strict so an exact
       // root sitting on an endpoint is returned as-is
      const float fp  = false_pos(lo, flo, hi, fhi);
      const bool okfp = (fp >= lo) && (fp <= hi);
      lam = okfp ? fp : 0.5f * (lo + hi);
    }
    lam = feas ? 0.0f : lam;

    // x = clip(y - lam*w); bitwise fixpoint early exit. State of the PGD map
    // is (x, lam_prev); if both are value-identical to the previous iteration
    // the remaining trajectory is identical, so breaking is exact.
    bool eq = (lam == lam_prev);
    lam_prev = lam;
    const v2f nl = {-lam, -lam};
#pragma unroll
    for (int p = 0; p < 4; ++p) {
      const v2f z = __builtin_elementwise_fma(nl, w[p], y[p]);
      const v2f nx = {clip01(z.x), clip01(z.y)};
      eq = eq && (nx.x == x[p].x) && (nx.y == x[p].y);
      x[p] = nx;
    }
    if (it > 0 && __all(eq)) break;  // per-wave exit; no barriers/LDS used
  }

  *reinterpret_cast<float4*>(out + base) =
      make_float4(x[0].x, x[0].y, x[1].x, x[1].y);
  *reinterpret_cast<float4*>(out + base + 4) =
      make_float4(x[2].x, x[2].y, x[3].x, x[3].y);
}

extern "C" void kernel_launch(void* const* d_in, const int* in_sizes, int n_in,
                              void* d_out, int out_size, void* d_ws, size_t ws_size,
                              hipStream_t stream) {
  const float* costs   = (const float*)d_in[0];
  const float* weights = (const float*)d_in[1];
  float* out           = (float*)d_out;

  const int n_rows  = in_sizes[0] / N_ITEMS;  // 16384
  const int threads = n_rows * 8;             // 8 lanes per row
  dim3 block(256);
  dim3 grid(threads / 256);
  pgd_knapsack<<<grid, block, 0, stream>>>(costs, weights, out);
}

// Round 4
// 160.636 us; speedup vs baseline: 4.2869x; 1.6213x over previous
//
#include <hip/hip_runtime.h>

// Problem constants (match reference)
#define N_ITEMS   64
#define CAPACITY  102.0f
#define N_PGD     120
#define ETA       0.1f
#define N_ILL     3    // Illinois/false-position evals after the warm probe

typedef float v2f __attribute__((ext_vector_type(2)));

// ---- DPP helpers: butterfly reductions over 8-lane groups ----------------
//   0xB1  = quad_perm [1,0,3,2]  -> lane ^ 1
//   0x4E  = quad_perm [2,3,0,1]  -> lane ^ 2
//   0x141 = row_half_mirror      -> lane ^ 7 within each 8-lane half
// FP add/max are commutative; all 8 lanes end bitwise-identical, so
// per-group decisions (bracket updates, lam) are uniform within the group.
template <int CTRL>
__device__ __forceinline__ float dpp_movf(float x) {
  return __builtin_bit_cast(
      float, __builtin_amdgcn_update_dpp(0, __builtin_bit_cast(int, x), CTRL,
                                         0xF, 0xF, true));
}

__device__ __forceinline__ float grp8_sum(float x) {
  x += dpp_movf<0xB1>(x);
  x += dpp_movf<0x4E>(x);
  x += dpp_movf<0x141>(x);
  return x;
}

__device__ __forceinline__ float grp8_max(float x) {
  x = fmaxf(x, dpp_movf<0xB1>(x));
  x = fmaxf(x, dpp_movf<0x4E>(x));
  x = fmaxf(x, dpp_movf<0x141>(x));
  return x;
}

__device__ __forceinline__ float clip01(float z) {
  return __builtin_amdgcn_fmed3f(z, 0.0f, 1.0f);  // single v_med3_f32
}

// g(lam) = sum_j w_j * clip(y_j - lam*w_j, 0, 1) over the 8-lane group.
__device__ __forceinline__ float eval_g(const v2f* __restrict__ w,
                                        const v2f* __restrict__ y, float lam) {
  const v2f nl = {-lam, -lam};
  const v2f z0 = __builtin_elementwise_fma(nl, w[0], y[0]);
  const v2f z1 = __builtin_elementwise_fma(nl, w[1], y[1]);
  const v2f z2 = __builtin_elementwise_fma(nl, w[2], y[2]);
  const v2f z3 = __builtin_elementwise_fma(nl, w[3], y[3]);
  const v2f t0 = {clip01(z0.x), clip01(z0.y)};
  const v2f t1 = {clip01(z1.x), clip01(z1.y)};
  const v2f t2 = {clip01(z2.x), clip01(z2.y)};
  const v2f t3 = {clip01(z3.x), clip01(z3.y)};
  v2f q0 = w[0] * t0;
  q0 = __builtin_elementwise_fma(w[1], t1, q0);
  v2f q1 = w[2] * t2;
  q1 = __builtin_elementwise_fma(w[3], t3, q1);
  const v2f q = q0 + q1;
  return grp8_sum(q.x + q.y);
}

// False-position estimate from the current bracket (flo > 0 > fhi).
__device__ __forceinline__ float false_pos(float lo, float flo, float hi,
                                           float fhi) {
  const float t = fhi * __builtin_amdgcn_rcpf(fhi - flo);
  return fmaf(-t, hi - lo, hi);  // hi - fhi*(hi-lo)/(fhi-flo), lands in (lo,hi)
}

// 8 lanes per row, 8 items per lane. 16384 rows -> 131072 threads.
__global__ __launch_bounds__(256, 2) void pgd_knapsack(
    const float* __restrict__ costs, const float* __restrict__ weights,
    float* __restrict__ out) {
  const int tid  = blockIdx.x * 256 + threadIdx.x;
  const int sub  = tid & 7;                 // lane within row-group
  const int base = (tid >> 3) * N_ITEMS + sub * 8;

  v2f w[4], ec[4], x[4], y[4];

  float B;     // bracket half-width: g(-B) = sum(w), g(+B) = 0 by construction
  float flo0;  // f(-B) = sum(w) - CAPACITY, exact, no eval needed
  {
    const float4 c0 = *reinterpret_cast<const float4*>(costs + base);
    const float4 c1 = *reinterpret_cast<const float4*>(costs + base + 4);
    const float4 w0 = *reinterpret_cast<const float4*>(weights + sub * 8);
    const float4 w1 = *reinterpret_cast<const float4*>(weights + sub * 8 + 4);
    w[0] = {w0.x, w0.y}; w[1] = {w0.z, w0.w};
    w[2] = {w1.x, w1.y}; w[3] = {w1.z, w1.w};
    const float cc[8] = {c0.x, c0.y, c0.z, c0.w, c1.x, c1.y, c1.z, c1.w};
    float cab = 0.0f;
#pragma unroll
    for (int p = 0; p < 4; ++p) {
      ec[p] = (v2f){ETA * cc[2 * p], ETA * cc[2 * p + 1]};
      y[p]  = (v2f){clip01(cc[2 * p]), clip01(cc[2 * p + 1])};
      x[p]  = (v2f){-1.0f, -1.0f};  // sentinel for the it=0 fixpoint compare
      cab = fmaxf(cab, fmaxf(fabsf(cc[2 * p]), fabsf(cc[2 * p + 1])));
    }
    cab = grp8_max(cab);
    // Every PGD iterate satisfies y_j in [-0.1 - eta*cab, 1 + eta*cab]
    // (since (1 - eta/||x||) * x_j in [-eta, 1]); with w_j >= 1 this makes
    // +-B a valid bracket: all coords clipped to 1 at -B, to 0 at +B.
    B = fmaf(ETA, cab, 1.1f) + 1e-3f;
    const v2f sw = (w[0] + w[1]) + (w[2] + w[3]);
    flo0 = grp8_sum(sw.x + sw.y) - CAPACITY;  // = 340 - 102, exact
  }
  const float fhi0 = -CAPACITY;  // f(+B) = 0 - CAPACITY, exact

  float lam_est = 0.0f;  // unclamped root estimate, warm start across iters

#pragma unroll 1
  for (int it = 0; it <= N_PGD; ++it) {
    if (it > 0) {
      // y = x + eta*(c - x/||x||) = (1 - eta/||x||)*x + eta*c
      v2f a = x[0] * x[0];
      a = __builtin_elementwise_fma(x[1], x[1], a);
      v2f b = x[2] * x[2];
      b = __builtin_elementwise_fma(x[3], x[3], b);
      const v2f ab = a + b;
      const float s2  = grp8_sum(ab.x + ab.y);
      const float inv = __builtin_amdgcn_rsqf(s2 + 1e-12f);
      const float s   = 1.0f - ETA * inv;
      const v2f sv = {s, s};
#pragma unroll
      for (int p = 0; p < 4; ++p)
        y[p] = __builtin_elementwise_fma(sv, x[p], ec[p]);
    }

    // ---- multiplier root-find on [-B, +B]: g(lam) = CAPACITY --------------
    // Root lam* <= 0 <=> constraint inactive; we clamp at the end, so no
    // separate feasibility evaluation is needed.
    float lo = -B, hi = B, flo = flo0, fhi = fhi0;
    float lam;
    bool prevpos;
    {  // warm probe: previous iteration's (unclamped) root estimate
      const float fp   = false_pos(lo, flo, hi, fhi);
      const bool okfp  = (fp > lo) && (fp < hi);
      const float cand = okfp ? fp : 0.0f;  // 0 is strictly inside [-B, B]
      const bool okw   = (lam_est > lo) && (lam_est < hi);
      lam = okw ? lam_est : cand;
      const float f = eval_g(w, y, lam) - CAPACITY;
      const bool pos = f > 0.0f;
      flo = pos ? f : flo;
      lo  = pos ? lam : lo;
      fhi = pos ? fhi : f;
      hi  = pos ? hi : lam;
      prevpos = pos;
    }
#pragma unroll 1
    for (int k = 0; k < N_ILL; ++k) {
      const float fp  = false_pos(lo, flo, hi, fhi);
      const bool okfp = (fp > lo) && (fp < hi);
      lam = okfp ? fp : 0.5f * (lo + hi);
      const float f = eval_g(w, y, lam) - CAPACITY;
      const bool pos = f > 0.0f;
      const bool rep = (pos == prevpos);  // Illinois anti-stagnation halving
      flo = pos ? f : (rep ? 0.5f * flo : flo);
      lo  = pos ? lam : lo;
      fhi = pos ? (rep ? 0.5f * fhi : fhi) : f;
      hi  = pos ? hi : lam;
      prevpos = pos;
    }
    {  // final derivative-free pick (no extra eval); non-strict so an exact
       // endpoint root is returned as-is (bitwise-stable in steady state)
      const float fp  = false_pos(lo, flo, hi, fhi);
      const bool okfp = (fp >= lo) && (fp <= hi);
      lam = okfp ? fp : 0.5f * (lo + hi);
    }
    const bool lam_stable = fabsf(lam - lam_est) <= 1e-6f;
    lam_est = lam;
    const float lam_use = fmaxf(lam, 0.0f);  // inactive constraint -> 0

    // x = clip(y - lam_use*w); eps-fixpoint exit. A per-element freeze at
    // 1e-7 bounds the remaining-trajectory deviation far below the 2e-2
    // output tolerance (immune to last-ulp limit cycles of lam).
    const v2f nl = {-lam_use, -lam_use};
    float dmax = 0.0f;
#pragma unroll
    for (int p = 0; p < 4; ++p) {
      const v2f z = __builtin_elementwise_fma(nl, w[p], y[p]);
      const v2f nx = {clip01(z.x), clip01(z.y)};
      dmax = fmaxf(dmax, fmaxf(fabsf(nx.x - x[p].x), fabsf(nx.y - x[p].y)));
      x[p] = nx;
    }
    const bool eq = (dmax <= 1e-7f) && lam_stable;
    if (it >= 4 && __all(eq)) break;  // per-wave exit; no barriers/LDS used
  }

  *reinterpret_cast<float4*>(out + base) =
      make_float4(x[0].x, x[0].y, x[1].x, x[1].y);
  *reinterpret_cast<float4*>(out + base + 4) =
      make_float4(x[2].x, x[2].y, x[3].x, x[3].y);
}

extern "C" void kernel_launch(void* const* d_in, const int* in_sizes, int n_in,
                              void* d_out, int out_size, void* d_ws, size_t ws_size,
                              hipStream_t stream) {
  const float* costs   = (const float*)d_in[0];
  const float* weights = (const float*)d_in[1];
  float* out           = (float*)d_out;

  const int n_rows  = in_sizes[0] / N_ITEMS;  // 16384
  const int threads = n_rows * 8;             // 8 lanes per row
  dim3 block(256);
  dim3 grid(threads / 256);
  pgd_knapsack<<<grid, block, 0, stream>>>(costs, weights, out);
}

// Round 5
// 143.883 us; speedup vs baseline: 4.7860x; 1.1164x over previous
//
#include <hip/hip_runtime.h>

// Problem constants (match reference)
#define N_ITEMS   64
#define CAPACITY  102.0f
#define N_PGD     120
#define ETA       0.1f
#define N_ILL     2    // Illinois/false-position evals after the warm probe

typedef float v2f __attribute__((ext_vector_type(2)));

// ---- DPP helpers: butterfly reductions over 8-lane groups ----------------
//   0xB1  = quad_perm [1,0,3,2]  -> lane ^ 1
//   0x4E  = quad_perm [2,3,0,1]  -> lane ^ 2
//   0x141 = row_half_mirror      -> lane ^ 7 within each 8-lane half
// FP add/max are commutative; all 8 lanes end bitwise-identical, so
// per-group decisions (bracket updates, lam) are uniform within the group.
template <int CTRL>
__device__ __forceinline__ float dpp_movf(float x) {
  return __builtin_bit_cast(
      float, __builtin_amdgcn_update_dpp(0, __builtin_bit_cast(int, x), CTRL,
                                         0xF, 0xF, true));
}

__device__ __forceinline__ float grp8_sum(float x) {
  x += dpp_movf<0xB1>(x);
  x += dpp_movf<0x4E>(x);
  x += dpp_movf<0x141>(x);
  return x;
}

__device__ __forceinline__ float grp8_max(float x) {
  x = fmaxf(x, dpp_movf<0xB1>(x));
  x = fmaxf(x, dpp_movf<0x4E>(x));
  x = fmaxf(x, dpp_movf<0x141>(x));
  return x;
}

__device__ __forceinline__ float clip01(float z) {
  return __builtin_amdgcn_fmed3f(z, 0.0f, 1.0f);  // single v_med3_f32
}

// g(lam) = sum_j w_j * clip(y_j - lam*w_j, 0, 1) over the 8-lane group.
__device__ __forceinline__ float eval_g(const v2f* __restrict__ w,
                                        const v2f* __restrict__ y, float lam) {
  const v2f nl = {-lam, -lam};
  const v2f z0 = __builtin_elementwise_fma(nl, w[0], y[0]);
  const v2f z1 = __builtin_elementwise_fma(nl, w[1], y[1]);
  const v2f z2 = __builtin_elementwise_fma(nl, w[2], y[2]);
  const v2f z3 = __builtin_elementwise_fma(nl, w[3], y[3]);
  const v2f t0 = {clip01(z0.x), clip01(z0.y)};
  const v2f t1 = {clip01(z1.x), clip01(z1.y)};
  const v2f t2 = {clip01(z2.x), clip01(z2.y)};
  const v2f t3 = {clip01(z3.x), clip01(z3.y)};
  v2f q0 = w[0] * t0;
  q0 = __builtin_elementwise_fma(w[1], t1, q0);
  v2f q1 = w[2] * t2;
  q1 = __builtin_elementwise_fma(w[3], t3, q1);
  const v2f q = q0 + q1;
  return grp8_sum(q.x + q.y);
}

// False-position estimate from the current bracket (flo > 0 > fhi).
__device__ __forceinline__ float false_pos(float lo, float flo, float hi,
                                           float fhi) {
  const float t = fhi * __builtin_amdgcn_rcpf(fhi - flo);
  return fmaf(-t, hi - lo, hi);  // hi - fhi*(hi-lo)/(fhi-flo), lands in (lo,hi)
}

// 8 lanes per row, 8 items per lane. 16384 rows -> 131072 threads.
__global__ __launch_bounds__(256, 2) void pgd_knapsack(
    const float* __restrict__ costs, const float* __restrict__ weights,
    float* __restrict__ out) {
  const int tid  = blockIdx.x * 256 + threadIdx.x;
  const int sub  = tid & 7;                 // lane within row-group
  const int base = (tid >> 3) * N_ITEMS + sub * 8;

  v2f w[4], ec[4], x[4], y[4];

  float B;     // bracket half-width: g(-B) = sum(w), g(+B) = 0 by construction
  float flo0;  // f(-B) = sum(w) - CAPACITY, exact, no eval needed
  {
    const float4 c0 = *reinterpret_cast<const float4*>(costs + base);
    const float4 c1 = *reinterpret_cast<const float4*>(costs + base + 4);
    const float4 w0 = *reinterpret_cast<const float4*>(weights + sub * 8);
    const float4 w1 = *reinterpret_cast<const float4*>(weights + sub * 8 + 4);
    w[0] = {w0.x, w0.y}; w[1] = {w0.z, w0.w};
    w[2] = {w1.x, w1.y}; w[3] = {w1.z, w1.w};
    const float cc[8] = {c0.x, c0.y, c0.z, c0.w, c1.x, c1.y, c1.z, c1.w};
    float cab = 0.0f;
#pragma unroll
    for (int p = 0; p < 4; ++p) {
      ec[p] = (v2f){ETA * cc[2 * p], ETA * cc[2 * p + 1]};
      y[p]  = (v2f){clip01(cc[2 * p]), clip01(cc[2 * p + 1])};
      x[p]  = (v2f){-1.0f, -1.0f};  // defined value for the it<16 dmax compare
      cab = fmaxf(cab, fmaxf(fabsf(cc[2 * p]), fabsf(cc[2 * p + 1])));
    }
    cab = grp8_max(cab);
    // Every PGD iterate satisfies y_j in [-0.1 - eta*cab, 1 + eta*cab]
    // (since (1 - eta/||x||) * x_j in [-eta, 1]); with w_j >= 1 this makes
    // +-B a valid bracket: all coords clipped to 1 at -B, to 0 at +B.
    B = fmaf(ETA, cab, 1.1f) + 1e-3f;
    const v2f sw = (w[0] + w[1]) + (w[2] + w[3]);
    flo0 = grp8_sum(sw.x + sw.y) - CAPACITY;  // = 340 - 102, exact
  }
  const float fhi0 = -CAPACITY;  // f(+B) = 0 - CAPACITY, exact

  float lam_est = 0.0f;  // unclamped root estimate, warm start across iters

#pragma unroll 1
  for (int it = 0; it <= N_PGD; ++it) {
    if (it > 0) {
      // y = x + eta*(c - x/||x||) = (1 - eta/||x||)*x + eta*c
      v2f a = x[0] * x[0];
      a = __builtin_elementwise_fma(x[1], x[1], a);
      v2f b = x[2] * x[2];
      b = __builtin_elementwise_fma(x[3], x[3], b);
      const v2f ab = a + b;
      const float s2  = grp8_sum(ab.x + ab.y);
      const float inv = __builtin_amdgcn_rsqf(s2 + 1e-12f);
      const float s   = 1.0f - ETA * inv;
      const v2f sv = {s, s};
#pragma unroll
      for (int p = 0; p < 4; ++p)
        y[p] = __builtin_elementwise_fma(sv, x[p], ec[p]);
    }

    // ---- multiplier root-find on [-B, +B]: g(lam) = CAPACITY --------------
    // Root lam* <= 0 <=> constraint inactive; we clamp at the end, so no
    // separate feasibility evaluation is needed.
    float lo = -B, hi = B, flo = flo0, fhi = fhi0;
    float lam;
    bool prevpos;
    {  // warm probe: previous iteration's (unclamped) root estimate
      const float fp   = false_pos(lo, flo, hi, fhi);
      const bool okfp  = (fp > lo) && (fp < hi);
      const float cand = okfp ? fp : 0.0f;  // 0 is strictly inside [-B, B]
      const bool okw   = (lam_est > lo) && (lam_est < hi);
      lam = okw ? lam_est : cand;
      const float f = eval_g(w, y, lam) - CAPACITY;
      const bool pos = f > 0.0f;
      flo = pos ? f : flo;
      lo  = pos ? lam : lo;
      fhi = pos ? fhi : f;
      hi  = pos ? hi : lam;
      prevpos = pos;
    }
#pragma unroll 1
    for (int k = 0; k < N_ILL; ++k) {
      const float fp  = false_pos(lo, flo, hi, fhi);
      const bool okfp = (fp > lo) && (fp < hi);
      lam = okfp ? fp : 0.5f * (lo + hi);
      const float f = eval_g(w, y, lam) - CAPACITY;
      const bool pos = f > 0.0f;
      const bool rep = (pos == prevpos);  // Illinois anti-stagnation halving
      flo = pos ? f : (rep ? 0.5f * flo : flo);
      lo  = pos ? lam : lo;
      fhi = pos ? (rep ? 0.5f * fhi : fhi) : f;
      hi  = pos ? hi : lam;
      prevpos = pos;
    }
    {  // final derivative-free pick (no extra eval); non-strict so an exact
       // endpoint root is returned as-is (stable under the warm start)
      const float fp  = false_pos(lo, flo, hi, fhi);
      const bool okfp = (fp >= lo) && (fp <= hi);
      lam = okfp ? fp : 0.5f * (lo + hi);
    }
    const bool lam_stable =
        fabsf(lam - lam_est) <= 1e-4f * (1.0f + fabsf(lam));
    lam_est = lam;
    const float lam_use = fmaxf(lam, 0.0f);  // inactive constraint -> 0

    // x = clip(y - lam_use*w); adaptive freeze exit. Even with zero
    // contraction, exiting when per-iter movement <= 2e-5 bounds remaining
    // drift by 120*2e-5 = 2.4e-3, far below the 2e-2 output tolerance;
    // near the fixpoint movement decays, so the true drift is smaller.
    const v2f nl = {-lam_use, -lam_use};
    float dmax = 0.0f;
#pragma unroll
    for (int p = 0; p < 4; ++p) {
      const v2f z = __builtin_elementwise_fma(nl, w[p], y[p]);
      const v2f nx = {clip01(z.x), clip01(z.y)};
      dmax = fmaxf(dmax, fmaxf(fabsf(nx.x - x[p].x), fabsf(nx.y - x[p].y)));
      x[p] = nx;
    }
    const bool eq = (dmax <= 2e-5f) && lam_stable;
    if (it >= 16 && __all(eq)) break;  // per-wave exit; no barriers/LDS used
  }

  *reinterpret_cast<float4*>(out + base) =
      make_float4(x[0].x, x[0].y, x[1].x, x[1].y);
  *reinterpret_cast<float4*>(out + base + 4) =
      make_float4(x[2].x, x[2].y, x[3].x, x[3].y);
}

extern "C" void kernel_launch(void* const* d_in, const int* in_sizes, int n_in,
                              void* d_out, int out_size, void* d_ws, size_t ws_size,
                              hipStream_t stream) {
  const float* costs   = (const float*)d_in[0];
  const float* weights = (const float*)d_in[1];
  float* out           = (float*)d_out;

  const int n_rows  = in_sizes[0] / N_ITEMS;  // 16384
  const int threads = n_rows * 8;             // 8 lanes per row
  dim3 block(256);
  dim3 grid(threads / 256);
  pgd_knapsack<<<grid, block, 0, stream>>>(costs, weights, out);
}

// Round 7
// 120.821 us; speedup vs baseline: 5.6996x; 1.1909x over previous
//
#include <hip/hip_runtime.h>

// Problem constants (match reference)
#define N_ITEMS   64
#define CAPACITY  102.0f
#define N_PGD     120
#define ETA       0.1f

typedef float v2f __attribute__((ext_vector_type(2)));

// ---- DPP helpers: butterfly reductions over 8-lane groups ----------------
//   0xB1  = quad_perm [1,0,3,2]  -> lane ^ 1
//   0x4E  = quad_perm [2,3,0,1]  -> lane ^ 2
//   0x141 = row_half_mirror      -> lane ^ 7 within each 8-lane half
// FP add/max are commutative; all 8 lanes end bitwise-identical, so
// per-group decisions (bracket updates, lam) are uniform within the group.
template <int CTRL>
__device__ __forceinline__ float dpp_movf(float x) {
  return __builtin_bit_cast(
      float, __builtin_amdgcn_update_dpp(0, __builtin_bit_cast(int, x), CTRL,
                                         0xF, 0xF, true));
}

__device__ __forceinline__ float grp8_sum(float x) {
  x += dpp_movf<0xB1>(x);
  x += dpp_movf<0x4E>(x);
  x += dpp_movf<0x141>(x);
  return x;
}

__device__ __forceinline__ float grp8_max(float x) {
  x = fmaxf(x, dpp_movf<0xB1>(x));
  x = fmaxf(x, dpp_movf<0x4E>(x));
  x = fmaxf(x, dpp_movf<0x141>(x));
  return x;
}

__device__ __forceinline__ float clip01(float z) {
  return __builtin_amdgcn_fmed3f(z, 0.0f, 1.0f);  // single v_med3_f32
}

// g(lam) = sum_j w_j * clip(y_j - lam*w_j, 0, 1) over the 8-lane group.
__device__ __forceinline__ float eval_g(const v2f* __restrict__ w,
                                        const v2f* __restrict__ y, float lam) {
  const v2f nl = {-lam, -lam};
  const v2f z0 = __builtin_elementwise_fma(nl, w[0], y[0]);
  const v2f z1 = __builtin_elementwise_fma(nl, w[1], y[1]);
  const v2f z2 = __builtin_elementwise_fma(nl, w[2], y[2]);
  const v2f z3 = __builtin_elementwise_fma(nl, w[3], y[3]);
  const v2f t0 = {clip01(z0.x), clip01(z0.y)};
  const v2f t1 = {clip01(z1.x), clip01(z1.y)};
  const v2f t2 = {clip01(z2.x), clip01(z2.y)};
  const v2f t3 = {clip01(z3.x), clip01(z3.y)};
  v2f q0 = w[0] * t0;
  q0 = __builtin_elementwise_fma(w[1], t1, q0);
  v2f q1 = w[2] * t2;
  q1 = __builtin_elementwise_fma(w[3], t3, q1);
  const v2f q = q0 + q1;
  return grp8_sum(q.x + q.y);
}

// False-position estimate from the bracket. Invariant: flo > 0 >= fhi
// (Illinois halving scales f-values by 0.5, which preserves signs), so
// fhi - flo < 0 strictly -> no divide-by-zero/NaN; the med3 clamp at the
// call site absorbs any rounding excursion outside [lo, hi].
__device__ __forceinline__ float false_pos(float lo, float flo, float hi,
                                           float fhi) {
  const float t = fhi * __builtin_amdgcn_rcpf(fhi - flo);
  return fmaf(-t, hi - lo, hi);  // hi - fhi*(hi-lo)/(fhi-flo)
}

// 8 lanes per row, 8 items per lane. 16384 rows -> 131072 threads.
__global__ __launch_bounds__(256, 2) void pgd_knapsack(
    const float* __restrict__ costs, const float* __restrict__ weights,
    float* __restrict__ out) {
  const int tid  = blockIdx.x * 256 + threadIdx.x;
  const int sub  = tid & 7;                 // lane within row-group
  const int base = (tid >> 3) * N_ITEMS + sub * 8;

  v2f w[4], ec[4], x[4], y[4];

  float B;     // bracket half-width: g(-B) = sum(w), g(+B) = 0 by construction
  float flo0;  // f(-B) = sum(w) - CAPACITY, exact, no eval needed
  {
    const float4 c0 = *reinterpret_cast<const float4*>(costs + base);
    const float4 c1 = *reinterpret_cast<const float4*>(costs + base + 4);
    const float4 w0 = *reinterpret_cast<const float4*>(weights + sub * 8);
    const float4 w1 = *reinterpret_cast<const float4*>(weights + sub * 8 + 4);
    w[0] = {w0.x, w0.y}; w[1] = {w0.z, w0.w};
    w[2] = {w1.x, w1.y}; w[3] = {w1.z, w1.w};
    const float cc[8] = {c0.x, c0.y, c0.z, c0.w, c1.x, c1.y, c1.z, c1.w};
    float cab = 0.0f;
#pragma unroll
    for (int p = 0; p < 4; ++p) {
      ec[p] = (v2f){ETA * cc[2 * p], ETA * cc[2 * p + 1]};
      y[p]  = (v2f){clip01(cc[2 * p]), clip01(cc[2 * p + 1])};
      cab = fmaxf(cab, fmaxf(fabsf(cc[2 * p]), fabsf(cc[2 * p + 1])));
    }
    cab = grp8_max(cab);
    // Every PGD iterate satisfies y_j in [-0.1 - eta*cab, 1 + eta*cab]
    // (since (1 - eta/||x||) * x_j in [-eta, 1]); with w_j >= 1 this makes
    // +-B a valid bracket: all coords clipped to 1 at -B, to 0 at +B.
    B = fmaf(ETA, cab, 1.1f) + 1e-3f;
    const v2f sw = (w[0] + w[1]) + (w[2] + w[3]);
    flo0 = grp8_sum(sw.x + sw.y) - CAPACITY;  // = 340 - 102, exact
  }
  const float fhi0 = -CAPACITY;  // f(+B) = 0 - CAPACITY, exact

  float lam_est = 0.0f;  // unclamped root estimate, warm start across iters

#pragma unroll 1
  for (int it = 0; it <= N_PGD; ++it) {
    if (it > 0) {
      // y = x + eta*(c - x/||x||) = (1 - eta/||x||)*x + eta*c
      v2f a = x[0] * x[0];
      a = __builtin_elementwise_fma(x[1], x[1], a);
      v2f b = x[2] * x[2];
      b = __builtin_elementwise_fma(x[3], x[3], b);
      const v2f ab = a + b;
      const float s2  = grp8_sum(ab.x + ab.y);
      const float inv = __builtin_amdgcn_rsqf(s2 + 1e-12f);
      const float s   = 1.0f - ETA * inv;
      const v2f sv = {s, s};
#pragma unroll
      for (int p = 0; p < 4; ++p)
        y[p] = __builtin_elementwise_fma(sv, x[p], ec[p]);
    }

    // ---- multiplier root-find on [-B, +B]: g(lam) = CAPACITY --------------
    // Root lam* <= 0 <=> constraint inactive; clamping at the end replaces a
    // separate feasibility evaluation. 3 evals: warm probe + 2 Illinois-
    // safeguarded false positions (R5-proven config; R6's 2-eval/no-Illinois
    // variant under-converged and flipped vertices).
    float lo = -B, hi = B, flo = flo0, fhi = fhi0;
    bool prevpos;

    // eval 1: warm probe at the previous iteration's root estimate
    float lam = __builtin_amdgcn_fmed3f(lam_est, lo, hi);
    {
      const float f = eval_g(w, y, lam) - CAPACITY;
      const bool pos = f > 0.0f;
      flo = pos ? f : flo;
      lo  = pos ? lam : lo;
      fhi = pos ? fhi : f;
      hi  = pos ? hi : lam;
      prevpos = pos;
    }

    // evals 2..3: false position with Illinois anti-stagnation halving
#pragma unroll
    for (int k = 0; k < 2; ++k) {
      lam = __builtin_amdgcn_fmed3f(false_pos(lo, flo, hi, fhi), lo, hi);
      const float f = eval_g(w, y, lam) - CAPACITY;
      const bool pos = f > 0.0f;
      const bool rep = (pos == prevpos);
      flo = pos ? f : (rep ? 0.5f * flo : flo);
      lo  = pos ? lam : lo;
      fhi = pos ? (rep ? 0.5f * fhi : fhi) : f;
      hi  = pos ? hi : lam;
      prevpos = pos;
    }

    // final derivative-free pick (no extra eval)
    lam = __builtin_amdgcn_fmed3f(false_pos(lo, flo, hi, fhi), lo, hi);
    lam_est = lam;
    const float lam_use = fmaxf(lam, 0.0f);  // inactive constraint -> 0

    // x = clip(y - lam_use*w). No early exit: on this non-contractive
    // projected iteration any exit loose enough to fire can freeze a row in
    // the wrong vertex (R6 failure, absmax 1.0).
    const v2f nl = {-lam_use, -lam_use};
#pragma unroll
    for (int p = 0; p < 4; ++p) {
      const v2f z = __builtin_elementwise_fma(nl, w[p], y[p]);
      x[p] = (v2f){clip01(z.x), clip01(z.y)};
    }
  }

  *reinterpret_cast<float4*>(out + base) =
      make_float4(x[0].x, x[0].y, x[1].x, x[1].y);
  *reinterpret_cast<float4*>(out + base + 4) =
      make_float4(x[2].x, x[2].y, x[3].x, x[3].y);
}

extern "C" void kernel_launch(void* const* d_in, const int* in_sizes, int n_in,
                              void* d_out, int out_size, void* d_ws, size_t ws_size,
                              hipStream_t stream) {
  const float* costs   = (const float*)d_in[0];
  const float* weights = (const float*)d_in[1];
  float* out           = (float*)d_out;

  const int n_rows  = in_sizes[0] / N_ITEMS;  // 16384
  const int threads = n_rows * 8;             // 8 lanes per row
  dim3 block(256);
  dim3 grid(threads / 256);
  pgd_knapsack<<<grid, block, 0, stream>>>(costs, weights, out);
}

// Round 9
// 117.100 us; speedup vs baseline: 5.8807x; 1.0318x over previous
//
#include <hip/hip_runtime.h>

// Problem constants (match reference)
#define N_ITEMS   64
#define CAPACITY  102.0f
#define N_PGD     120
#define ETA       0.1f

typedef float v2f __attribute__((ext_vector_type(2)));

// ---- DPP helpers: butterfly reductions over 4-lane quads ------------------
//   0xB1 = quad_perm [1,0,3,2] -> lane ^ 1
//   0x4E = quad_perm [2,3,0,1] -> lane ^ 2
// Both are quad-local, so a 4-lane problem-group never leaks into neighbors.
// FP add/max are commutative; all 4 lanes end bitwise-identical, so per-group
// decisions (bracket updates, lam) are uniform within the group.
template <int CTRL>
__device__ __forceinline__ float dpp_movf(float x) {
  return __builtin_bit_cast(
      float, __builtin_amdgcn_update_dpp(0, __builtin_bit_cast(int, x), CTRL,
                                         0xF, 0xF, true));
}

__device__ __forceinline__ float grp4_sum(float x) {
  x += dpp_movf<0xB1>(x);
  x += dpp_movf<0x4E>(x);
  return x;
}

__device__ __forceinline__ float grp4_max(float x) {
  x = fmaxf(x, dpp_movf<0xB1>(x));
  x = fmaxf(x, dpp_movf<0x4E>(x));
  return x;
}

__device__ __forceinline__ float clip01(float z) {
  return __builtin_amdgcn_fmed3f(z, 0.0f, 1.0f);  // single v_med3_f32
}

// g(lam) = sum_j w_j * clip(y_j - lam*w_j, 0, 1) over the 4-lane group.
// 16 items/lane in 8 v2f registers; 4 independent accumulation chains.
__device__ __forceinline__ float eval_g(const v2f* __restrict__ w,
                                        const v2f* __restrict__ y, float lam) {
  const v2f nl = {-lam, -lam};
  v2f q[4];
#pragma unroll
  for (int p = 0; p < 4; ++p) {
    const v2f z0 = __builtin_elementwise_fma(nl, w[2 * p], y[2 * p]);
    const v2f z1 = __builtin_elementwise_fma(nl, w[2 * p + 1], y[2 * p + 1]);
    const v2f t0 = {clip01(z0.x), clip01(z0.y)};
    const v2f t1 = {clip01(z1.x), clip01(z1.y)};
    const v2f qq = w[2 * p] * t0;
    q[p] = __builtin_elementwise_fma(w[2 * p + 1], t1, qq);
  }
  const v2f qs = (q[0] + q[1]) + (q[2] + q[3]);
  return grp4_sum(qs.x + qs.y);
}

// False-position estimate from the bracket. Invariant: flo > 0 >= fhi
// (Illinois halving scales f-values by 0.5, preserving signs), so
// fhi - flo < 0 strictly -> no divide-by-zero/NaN; the med3 clamp at the
// call site absorbs any rounding excursion outside [lo, hi].
__device__ __forceinline__ float false_pos(float lo, float flo, float hi,
                                           float fhi) {
  const float t = fhi * __builtin_amdgcn_rcpf(fhi - flo);
  return fmaf(-t, hi - lo, hi);  // hi - fhi*(hi-lo)/(fhi-flo)
}

// 4 lanes per row, 16 items per lane. 16384 rows -> 65536 threads
// (1024 waves = 1 wave/SIMD; per-eval bookkeeping halves vs 8-lane and
// reductions are 2 quad-perm DPP steps instead of 3).
__global__ __launch_bounds__(256, 1) void pgd_knapsack(
    const float* __restrict__ costs, const float* __restrict__ weights,
    float* __restrict__ out) {
  const int tid  = blockIdx.x * 256 + threadIdx.x;
  const int sub  = tid & 3;                 // lane within row-group
  const int base = (tid >> 2) * N_ITEMS + sub * 16;

  v2f w[8], ec[8], x[8], y[8];

  float B;     // bracket half-width: g(-B) = sum(w), g(+B) = 0 by construction
  float flo0;  // f(-B) = sum(w) - CAPACITY, exact, no eval needed
  {
    float cab = 0.0f;
#pragma unroll
    for (int u = 0; u < 4; ++u) {
      const float4 cq = *reinterpret_cast<const float4*>(costs + base + 4 * u);
      const float4 wq =
          *reinterpret_cast<const float4*>(weights + sub * 16 + 4 * u);
      w[2 * u]      = (v2f){wq.x, wq.y};
      w[2 * u + 1]  = (v2f){wq.z, wq.w};
      ec[2 * u]     = (v2f){ETA * cq.x, ETA * cq.y};
      ec[2 * u + 1] = (v2f){ETA * cq.z, ETA * cq.w};
      y[2 * u]      = (v2f){clip01(cq.x), clip01(cq.y)};
      y[2 * u + 1]  = (v2f){clip01(cq.z), clip01(cq.w)};
      cab = fmaxf(cab, fmaxf(fmaxf(fabsf(cq.x), fabsf(cq.y)),
                             fmaxf(fabsf(cq.z), fabsf(cq.w))));
    }
    cab = grp4_max(cab);
    // Every PGD iterate satisfies y_j in [-0.1 - eta*cab, 1 + eta*cab]
    // (since (1 - eta/||x||) * x_j in [-eta, 1]); with w_j >= 1 this makes
    // +-B a valid bracket: all coords clipped to 1 at -B, to 0 at +B.
    B = fmaf(ETA, cab, 1.1f) + 1e-3f;
    v2f sw = (w[0] + w[1]) + (w[2] + w[3]);
    sw = sw + ((w[4] + w[5]) + (w[6] + w[7]));
    flo0 = grp4_sum(sw.x + sw.y) - CAPACITY;  // = 340 - 102, exact
  }
  const float fhi0 = -CAPACITY;  // f(+B) = 0 - CAPACITY, exact

  float lam_est = 0.0f;  // unclamped root estimate, warm start across iters

#pragma unroll 1
  for (int it = 0; it <= N_PGD; ++it) {
    if (it > 0) {
      // y = x + eta*(c - x/||x||) = (1 - eta/||x||)*x + eta*c
      v2f a = x[0] * x[0];
      a = __builtin_elementwise_fma(x[1], x[1], a);
      v2f b = x[2] * x[2];
      b = __builtin_elementwise_fma(x[3], x[3], b);
      v2f c2 = x[4] * x[4];
      c2 = __builtin_elementwise_fma(x[5], x[5], c2);
      v2f d = x[6] * x[6];
      d = __builtin_elementwise_fma(x[7], x[7], d);
      const v2f ab = (a + b) + (c2 + d);
      const float s2  = grp4_sum(ab.x + ab.y);
      const float inv = __builtin_amdgcn_rsqf(s2 + 1e-12f);
      const float s   = 1.0f - ETA * inv;
      const v2f sv = {s, s};
#pragma unroll
      for (int p = 0; p < 8; ++p)
        y[p] = __builtin_elementwise_fma(sv, x[p], ec[p]);
    }

    // ---- multiplier root-find on [-B, +B]: g(lam) = CAPACITY --------------
    // Root lam* <= 0 <=> constraint inactive; clamping at the end replaces a
    // separate feasibility evaluation. R7-proven solver: warm probe + 2
    // Illinois-safeguarded false positions + exact final pick. 3 evals is the
    // verified minimum (R8: 2 evals under-converges lam and flips vertices).
    // NO early exit (R6: freezing a non-contractive iteration flips vertices).
    float lo = -B, hi = B, flo = flo0, fhi = fhi0;
    bool prevpos;

    // eval 1: warm probe at the previous iteration's root estimate
    float lam = __builtin_amdgcn_fmed3f(lam_est, lo, hi);
    {
      const float f = eval_g(w, y, lam) - CAPACITY;
      const bool pos = f > 0.0f;
      flo = pos ? f : flo;
      lo  = pos ? lam : lo;
      fhi = pos ? fhi : f;
      hi  = pos ? hi : lam;
      prevpos = pos;
    }

    // evals 2..3: false position with Illinois anti-stagnation halving
#pragma unroll
    for (int k = 0; k < 2; ++k) {
      lam = __builtin_amdgcn_fmed3f(false_pos(lo, flo, hi, fhi), lo, hi);
      const float f = eval_g(w, y, lam) - CAPACITY;
      const bool pos = f > 0.0f;
      const bool rep = (pos == prevpos);
      flo = pos ? f : (rep ? 0.5f * flo : flo);
      lo  = pos ? lam : lo;
      fhi = pos ? (rep ? 0.5f * fhi : fhi) : f;
      hi  = pos ? hi : lam;
      prevpos = pos;
    }

    // final derivative-free pick (no extra eval)
    lam = __builtin_amdgcn_fmed3f(false_pos(lo, flo, hi, fhi), lo, hi);
    lam_est = lam;
    const float lam_use = fmaxf(lam, 0.0f);  // inactive constraint -> 0

    // x = clip(y - lam_use*w)
    const v2f nl = {-lam_use, -lam_use};
#pragma unroll
    for (int p = 0; p < 8; ++p) {
      const v2f z = __builtin_elementwise_fma(nl, w[p], y[p]);
      x[p] = (v2f){clip01(z.x), clip01(z.y)};
    }
  }

#pragma unroll
  for (int u = 0; u < 4; ++u) {
    *reinterpret_cast<float4*>(out + base + 4 * u) =
        make_float4(x[2 * u].x, x[2 * u].y, x[2 * u + 1].x, x[2 * u + 1].y);
  }
}

extern "C" void kernel_launch(void* const* d_in, const int* in_sizes, int n_in,
                              void* d_out, int out_size, void* d_ws, size_t ws_size,
                              hipStream_t stream) {
  const float* costs   = (const float*)d_in[0];
  const float* weights = (const float*)d_in[1];
  float* out           = (float*)d_out;

  const int n_rows  = in_sizes[0] / N_ITEMS;  // 16384
  const int threads = n_rows * 4;             // 4 lanes per row
  dim3 block(256);
  dim3 grid(threads / 256);
  pgd_knapsack<<<grid, block, 0, stream>>>(costs, weights, out);
}

// Round 10
// 114.952 us; speedup vs baseline: 5.9906x; 1.0187x over previous
//
#include <hip/hip_runtime.h>

// Problem constants (match reference)
#define N_ITEMS   64
#define CAPACITY  102.0f
#define N_PGD     120
#define ETA       0.1f

typedef float v2f __attribute__((ext_vector_type(2)));

// ---- DPP helpers: butterfly reductions over 4-lane quads ------------------
//   0xB1 = quad_perm [1,0,3,2] -> lane ^ 1
//   0x4E = quad_perm [2,3,0,1] -> lane ^ 2
// Both are quad-local, so a 4-lane problem-group never leaks into neighbors.
// FP add/max are commutative; all 4 lanes end bitwise-identical, so per-group
// decisions (bracket updates, lam) are uniform within the group.
template <int CTRL>
__device__ __forceinline__ float dpp_movf(float x) {
  return __builtin_bit_cast(
      float, __builtin_amdgcn_update_dpp(0, __builtin_bit_cast(int, x), CTRL,
                                         0xF, 0xF, true));
}

__device__ __forceinline__ float grp4_sum(float x) {
  x += dpp_movf<0xB1>(x);
  x += dpp_movf<0x4E>(x);
  return x;
}

__device__ __forceinline__ float grp4_max(float x) {
  x = fmaxf(x, dpp_movf<0xB1>(x));
  x = fmaxf(x, dpp_movf<0x4E>(x));
  return x;
}

__device__ __forceinline__ float clip01(float z) {
  return __builtin_amdgcn_fmed3f(z, 0.0f, 1.0f);  // single v_med3_f32
}

// False-position estimate from the bracket. Invariant: flo > 0 >= fhi
// (Illinois halving scales f-values by 0.5, preserving signs), so
// fhi - flo < 0 strictly -> no divide-by-zero/NaN; the med3 clamp at the
// call site absorbs any rounding excursion outside [lo, hi].
__device__ __forceinline__ float false_pos(float lo, float flo, float hi,
                                           float fhi) {
  const float t = fhi * __builtin_amdgcn_rcpf(fhi - flo);
  return fmaf(-t, hi - lo, hi);  // hi - fhi*(hi-lo)/(fhi-flo)
}

// 4 lanes per row, 16 items per lane. 16384 rows -> 65536 threads
// (1024 waves = 1 wave/SIMD).
__global__ __launch_bounds__(256, 1) void pgd_knapsack(
    const float* __restrict__ costs, const float* __restrict__ weights,
    float* __restrict__ out) {
  const int tid  = blockIdx.x * 256 + threadIdx.x;
  const int sub  = tid & 3;                 // lane within row-group
  const int base = (tid >> 2) * N_ITEMS + sub * 16;

  v2f w[8], ec[8], x[8], y[8];

  float B;     // bracket half-width: g(-B) = sum(w), g(+B) = 0 by construction
  float flo0;  // f(-B) = sum(w) - CAPACITY, exact, no eval needed
  {
    float cab = 0.0f;
#pragma unroll
    for (int u = 0; u < 4; ++u) {
      const float4 cq = *reinterpret_cast<const float4*>(costs + base + 4 * u);
      const float4 wq =
          *reinterpret_cast<const float4*>(weights + sub * 16 + 4 * u);
      w[2 * u]      = (v2f){wq.x, wq.y};
      w[2 * u + 1]  = (v2f){wq.z, wq.w};
      ec[2 * u]     = (v2f){ETA * cq.x, ETA * cq.y};
      ec[2 * u + 1] = (v2f){ETA * cq.z, ETA * cq.w};
      y[2 * u]      = (v2f){clip01(cq.x), clip01(cq.y)};
      y[2 * u + 1]  = (v2f){clip01(cq.z), clip01(cq.w)};
      cab = fmaxf(cab, fmaxf(fmaxf(fabsf(cq.x), fabsf(cq.y)),
                             fmaxf(fabsf(cq.z), fabsf(cq.w))));
    }
    cab = grp4_max(cab);
    // Every PGD iterate satisfies y_j in [-0.1 - eta*cab, 1 + eta*cab]
    // (since (1 - eta/||x||) * x_j in [-eta, 1]); with w_j >= 1 this makes
    // +-B a valid bracket: all coords clipped to 1 at -B, to 0 at +B.
    B = fmaf(ETA, cab, 1.1f) + 1e-3f;
    v2f sw = (w[0] + w[1]) + (w[2] + w[3]);
    sw = sw + ((w[4] + w[5]) + (w[6] + w[7]));
    flo0 = grp4_sum(sw.x + sw.y) - CAPACITY;  // = 340 - 102, exact
  }
  const float fhi0 = -CAPACITY;  // f(+B) = 0 - CAPACITY, exact

  float lam_est = 0.0f;  // unclamped root estimate, warm start across iters

  // g(lam) - CAPACITY over the 4-lane group (16 items/lane, 4 indep chains).
  auto eval_f = [&](float lam) -> float {
    const v2f nl = {-lam, -lam};
    v2f q[4];
#pragma unroll
    for (int p = 0; p < 4; ++p) {
      const v2f z0 = __builtin_elementwise_fma(nl, w[2 * p], y[2 * p]);
      const v2f z1 = __builtin_elementwise_fma(nl, w[2 * p + 1], y[2 * p + 1]);
      const v2f t0 = {clip01(z0.x), clip01(z0.y)};
      const v2f t1 = {clip01(z1.x), clip01(z1.y)};
      const v2f qq = w[2 * p] * t0;
      q[p] = __builtin_elementwise_fma(w[2 * p + 1], t1, qq);
    }
    const v2f qs = (q[0] + q[1]) + (q[2] + q[3]);
    return grp4_sum(qs.x + qs.y) - CAPACITY;
  };

  // ---- multiplier root-find on [-B, +B] + epilogue x = clip(y - lam*w) ----
  // R7-proven solver: warm probe + 2 Illinois false positions + exact final
  // pick. 3 evals is the verified accuracy floor (R8: 2 evals flips
  // vertices); NO data-dependent freeze/exit (R6: flips vertices). The only
  // sanctioned shortcut: skip eval 3 when EVERY group in the wave already has
  // bracket width <= 1e-5 after eval 2 (wave-uniform branch). Skipping then
  // perturbs lam by <= 1e-5 (one-shot, non-accumulating: each iteration
  // re-solves lam from scratch), i.e. x by <= w*1e-5 <= 1e-4 << 2e-2.
  auto solve_project = [&]() {
    float lo = -B, hi = B, flo = flo0, fhi = fhi0;
    bool prevpos;

    // eval 1: warm probe at the previous iteration's root estimate
    float lam = __builtin_amdgcn_fmed3f(lam_est, lo, hi);
    {
      const float f = eval_f(lam);
      const bool pos = f > 0.0f;
      flo = pos ? f : flo;
      lo  = pos ? lam : lo;
      fhi = pos ? fhi : f;
      hi  = pos ? hi : lam;
      prevpos = pos;
    }

    // eval 2: false position with Illinois anti-stagnation halving
    {
      lam = __builtin_amdgcn_fmed3f(false_pos(lo, flo, hi, fhi), lo, hi);
      const float f = eval_f(lam);
      const bool pos = f > 0.0f;
      const bool rep = (pos == prevpos);
      flo = pos ? f : (rep ? 0.5f * flo : flo);
      lo  = pos ? lam : lo;
      fhi = pos ? (rep ? 0.5f * fhi : fhi) : f;
      hi  = pos ? hi : lam;
      prevpos = pos;
    }

    // eval 3: identical Illinois step, skipped only if the whole wave's
    // brackets have already collapsed below 1e-5.
    const bool tiny = (hi - lo) <= 1e-5f;
    if (!__all(tiny)) {
      lam = __builtin_amdgcn_fmed3f(false_pos(lo, flo, hi, fhi), lo, hi);
      const float f = eval_f(lam);
      const bool pos = f > 0.0f;
      const bool rep = (pos == prevpos);
      flo = pos ? f : (rep ? 0.5f * flo : flo);
      lo  = pos ? lam : lo;
      fhi = pos ? (rep ? 0.5f * fhi : fhi) : f;
      hi  = pos ? hi : lam;
    }

    // final derivative-free pick (no extra eval)
    lam = __builtin_amdgcn_fmed3f(false_pos(lo, flo, hi, fhi), lo, hi);
    lam_est = lam;
    const float lam_use = fmaxf(lam, 0.0f);  // inactive constraint -> 0

    const v2f nl = {-lam_use, -lam_use};
#pragma unroll
    for (int p = 0; p < 8; ++p) {
      const v2f z = __builtin_elementwise_fma(nl, w[p], y[p]);
      x[p] = (v2f){clip01(z.x), clip01(z.y)};
    }
  };

  // Iteration 0 peeled: y is already clip01(c).
  solve_project();

#pragma unroll 2
  for (int it = 1; it <= N_PGD; ++it) {
    // y = x + eta*(c - x/||x||) = (1 - eta/||x||)*x + eta*c
    v2f a = x[0] * x[0];
    a = __builtin_elementwise_fma(x[1], x[1], a);
    v2f b = x[2] * x[2];
    b = __builtin_elementwise_fma(x[3], x[3], b);
    v2f c2 = x[4] * x[4];
    c2 = __builtin_elementwise_fma(x[5], x[5], c2);
    v2f d = x[6] * x[6];
    d = __builtin_elementwise_fma(x[7], x[7], d);
    const v2f ab = (a + b) + (c2 + d);
    const float s2  = grp4_sum(ab.x + ab.y);
    const float inv = __builtin_amdgcn_rsqf(s2 + 1e-12f);
    const float s   = 1.0f - ETA * inv;
    const v2f sv = {s, s};
#pragma unroll
    for (int p = 0; p < 8; ++p)
      y[p] = __builtin_elementwise_fma(sv, x[p], ec[p]);

    solve_project();
  }

#pragma unroll
  for (int u = 0; u < 4; ++u) {
    *reinterpret_cast<float4*>(out + base + 4 * u) =
        make_float4(x[2 * u].x, x[2 * u].y, x[2 * u + 1].x, x[2 * u + 1].y);
  }
}

extern "C" void kernel_launch(void* const* d_in, const int* in_sizes, int n_in,
                              void* d_out, int out_size, void* d_ws, size_t ws_size,
                              hipStream_t stream) {
  const float* costs   = (const float*)d_in[0];
  const float* weights = (const float*)d_in[1];
  float* out           = (float*)d_out;

  const int n_rows  = in_sizes[0] / N_ITEMS;  // 16384
  const int threads = n_rows * 4;             // 4 lanes per row
  dim3 block(256);
  dim3 grid(threads / 256);
  pgd_knapsack<<<grid, block, 0, stream>>>(costs, weights, out);
}